// Round 5
// baseline (828.965 us; speedup 1.0000x reference)
//
#include <hip/hip_runtime.h>
#include <cstdint>
#include <cstddef>

#define DIM    256
#define NE     2048
#define NROWS  65536

// d_out flat fp32 layout: quantize_st | diff | embed_ind | perplexity
#define OFF_DIFF ((size_t)16777216)
#define OFF_IND  ((size_t)16777217)
#define OFF_PERP ((size_t)16842753)

// d_ws byte layout
#define WS_DIFF   0                       // double
#define WS_NFLAG  8                       // int
#define WS_CNT    64                      // int[2048]
#define WS_EN     8256                    // float[2048]  ||e||^2
#define WS_FLAG   16448                   // int[4096] flagged rows
#define WS_ET     32832                   // float[2048*256] embedT
#define WS_BPH    2129984                 // _Float16[2048*256] packed B hi
#define FLAG_CAP  4096

typedef __attribute__((ext_vector_type(8)))  _Float16 half8;
typedef __attribute__((ext_vector_type(16))) float    float16v;

__device__ __forceinline__ float16v mfma32(half8 a, half8 b, float16v c) {
    return __builtin_amdgcn_mfma_f32_32x32x16_f16(a, b, c, 0, 0, 0);
}

__device__ __forceinline__ void gld16(const void* g, void* l) {
    __builtin_amdgcn_global_load_lds((const __attribute__((address_space(1))) void*)g,
                                     (__attribute__((address_space(3))) void*)l,
                                     16, 0, 0);
}

// ---------------- prep: ||e_j||^2, double-accurate, 8 threads/col ----------------
__global__ __launch_bounds__(256) void k_prep(const float* __restrict__ embed,
                                              float* __restrict__ enorm) {
    __shared__ double red[256];
    const int tid = threadIdx.x;
    const int cl  = tid & 31, seg = tid >> 5;
    const int col = blockIdx.x * 32 + cl;
    double s = 0.0;
#pragma unroll 8
    for (int k = seg * 32; k < seg * 32 + 32; ++k) {
        float e = embed[(size_t)k * NE + col];
        s += (double)e * (double)e;
    }
    red[tid] = s;
    __syncthreads();
    if (seg == 0) {
        double t = 0.0;
#pragma unroll
        for (int h = 0; h < 8; ++h) t += red[cl + 32 * h];
        enorm[col] = (float)t;
    }
}

// ---------------- pack B-hi into 32x32x16 fragment order + embedT ----------------
// lane holds B[k = tfrag*16 + (lane>>5)*8 + j][col = nc*32 + (lane&31)], j=0..7
__global__ __launch_bounds__(256) void k_pack(const float* __restrict__ embed,
                                              _Float16* __restrict__ bph,
                                              float* __restrict__ embedT) {
    int tt    = blockIdx.x * 256 + threadIdx.x;   // 0..65535
    int nc    = tt >> 10;
    int tfrag = (tt >> 6) & 15;
    int lane  = tt & 63;
    int col   = nc * 32 + (lane & 31);
    int k0    = tfrag * 16 + (lane >> 5) * 8;
    half8 h;
#pragma unroll
    for (int j = 0; j < 8; ++j) {
        float e = embed[(size_t)(k0 + j) * NE + col];
        h[j] = (_Float16)e;
        embedT[(size_t)col * DIM + k0 + j] = e;
    }
    *(half8*)((char*)bph + (size_t)nc * 16384 + (size_t)tfrag * 1024 + (size_t)lane * 16) = h;
}

// ---------------- main fused MFMA kernel (2-term hi-B) ----------------
__global__ __launch_bounds__(256, 2) void k_gemm(
    const float* __restrict__ inp,
    const _Float16* __restrict__ bph,
    const float* __restrict__ enorm,
    const float* __restrict__ embedT,
    float* __restrict__ out,
    int* __restrict__ counts,
    double* __restrict__ diffacc,
    int* __restrict__ nflag,
    int* __restrict__ flags)
{
    __shared__ __align__(16) char ldsB[2][16384];   // dbuf, B-hi 16 KB per nc-chunk
    const int tid  = threadIdx.x;
    const int w    = tid >> 6;
    const int lane = tid & 63;
    const int m    = lane & 31;       // col (B/C) or row (A) within tile
    const int mw   = blockIdx.x * 128 + w * 32;

    // ---- A: 32 rows/wave stationary, f16 hi+lo split (exact to ~2^-22) ----
    half8 ah[16], al[16];
    {
        const float* xr = inp + (size_t)(mw + m) * DIM + (lane >> 5) * 8;
#pragma unroll
        for (int t = 0; t < 16; ++t) {
            float4 f0 = *(const float4*)(xr + t * 16);
            float4 f1 = *(const float4*)(xr + t * 16 + 4);
            float fs[8] = {f0.x, f0.y, f0.z, f0.w, f1.x, f1.y, f1.z, f1.w};
            half8 hh, ll;
#pragma unroll
            for (int j = 0; j < 8; ++j) {
                _Float16 xh = (_Float16)fs[j];
                hh[j] = xh;
                ll[j] = (_Float16)(fs[j] - (float)xh);
            }
            ah[t] = hh;
            al[t] = ll;
        }
    }

    // packed top-2 per C-reg slot
    int P1[16], P2[16];
#pragma unroll
    for (int r = 0; r < 16; ++r) { P1[r] = (int)0x80000000; P2[r] = (int)0x80000000; }

    // stage nc=0: 16 segs of 1 KB, wave w stages 4
#pragma unroll
    for (int s = 0; s < 4; ++s) {
        int seg = w * 4 + s;
        gld16((const char*)bph + seg * 1024 + lane * 16, &ldsB[0][0] + seg * 1024);
    }
    __syncthreads();

    for (int nc = 0; nc < 64; ++nc) {
        int pn = nc & 1;
        if (nc < 63) {
            const char* src = (const char*)bph + (size_t)(nc + 1) * 16384;
            char* dst = &ldsB[pn ^ 1][0];
#pragma unroll
            for (int s = 0; s < 4; ++s) {
                int seg = w * 4 + s;
                gld16(src + seg * 1024 + lane * 16, dst + seg * 1024);
            }
        }

        const char* bb = &ldsB[pn][0] + lane * 16;
        float16v accA = {}, accB = {};
#pragma unroll
        for (int t = 0; t < 16; ++t) {
            half8 bh = *(const half8*)(bb + t * 1024);
            accA = mfma32(ah[t], bh, accA);
            accB = mfma32(al[t], bh, accB);
        }

        float en  = enorm[nc * 32 + m];
        float enc = fmaf(en, -1024.0f, 262144.0f);   // (128 - en/2)*2048
        int colp  = nc * 32 + m;
#pragma unroll
        for (int r = 0; r < 16; ++r) {
            float sf = fmaf(accA[r] + accB[r], 2048.0f, enc);
            sf = __builtin_amdgcn_fmed3f(sf, -1048064.0f, 1048064.0f);
            int si = (int)sf;
            int p  = (int)(((unsigned)si << 11) | (unsigned)colp);
            int mn = (P1[r] < p) ? P1[r] : p;
            P2[r]  = (P2[r] > mn) ? P2[r] : mn;
            P1[r]  = (P1[r] > p) ? P1[r] : p;
        }
        __syncthreads();
    }

    // ---- cross-lane top-2 merge over the 32 col-lanes (per half) ----
#pragma unroll
    for (int r = 0; r < 16; ++r) {
        int p1 = P1[r], p2 = P2[r];
#pragma unroll
        for (int msk = 1; msk < 32; msk <<= 1) {
            int o1 = __shfl_xor(p1, msk);
            int o2 = __shfl_xor(p2, msk);
            int mx2 = (p2 > o2) ? p2 : o2;
            int mn1 = (p1 < o1) ? p1 : o1;
            p2 = (mx2 > mn1) ? mx2 : mn1;
            p1 = (p1 > o1) ? p1 : o1;
        }
        P1[r] = p1; P2[r] = p2;
    }

    // ---- epilogue: exact fp32 rescore of top-2, margin flag, gather, write ----
    double dsum = 0.0;
#pragma unroll
    for (int rr = 0; rr < 32; ++rr) {
        const int reg = (rr & 3) | (((rr >> 3) & 3) << 2);
        const int src = ((rr >> 2) & 1) << 5;
        int p1row = __shfl(P1[reg], src);
        int p2row = __shfl(P2[reg], src);
        int i1 = p1row & 2047;
        int i2 = p2row & 2047;
        float v2a = (float)(p2row >> 11) * (1.0f / 1024.0f) - 256.0f;  // approx 2nd, full scale
        int row = mw + rr;
        float4 xv = *(const float4*)(inp    + (size_t)row * DIM + lane * 4);
        float4 e1 = *(const float4*)(embedT + (size_t)i1  * DIM + lane * 4);
        float4 e2 = *(const float4*)(embedT + (size_t)i2  * DIM + lane * 4);
        float d1 = xv.x * e1.x + xv.y * e1.y + xv.z * e1.z + xv.w * e1.w;
        float d2 = xv.x * e2.x + xv.y * e2.y + xv.z * e2.z + xv.w * e2.w;
#pragma unroll
        for (int msk = 1; msk < 64; msk <<= 1) {
            d1 += __shfl_xor(d1, msk);
            d2 += __shfl_xor(d2, msk);
        }
        float s1 = 2.f * d1 - enorm[i1];
        float s2 = 2.f * d2 - enorm[i2];
        bool take2 = (s2 > s1) || (s2 == s1 && i2 < i1);
        int win = take2 ? i2 : i1;
        float sW = take2 ? s2 : s1;
        float4 qv = take2 ? e2 : e1;
        *(float4*)(out + (size_t)row * DIM + lane * 4) = qv;
        float dx = qv.x - xv.x, dy = qv.y - xv.y;
        float dz = qv.z - xv.z, dw = qv.w - xv.w;
        dsum += (double)(dx * dx + dy * dy + dz * dz + dw * dw);
        if (lane == 0) {
            out[OFF_IND + row] = (float)win;
            atomicAdd(&counts[win], 1);
            if (sW - v2a < 0.15f) {          // untracked-column safety margin (~18 sigma)
                int fi = atomicAdd(nflag, 1);
                if (fi < FLAG_CAP) flags[fi] = row;
            }
        }
    }
#pragma unroll
    for (int msk = 1; msk < 64; msk <<= 1) dsum += __shfl_xor(dsum, msk);
    if (lane == 0) atomicAdd(diffacc, dsum);
}

// ---------------- cleanup: exact fp32 full rescan of flagged rows ----------------
__global__ __launch_bounds__(256) void k_clean(
    const float* __restrict__ inp,
    const float* __restrict__ embed,
    const float* __restrict__ embedT,
    const float* __restrict__ enorm,
    float* __restrict__ out,
    int* __restrict__ counts,
    double* __restrict__ diffacc,
    const int* __restrict__ nflagp,
    const int* __restrict__ flags)
{
    __shared__ float XsT[DIM][64];
    __shared__ int rowsS[64];
    __shared__ int newS[64];
    __shared__ double redS[4];
    int nf = *nflagp; if (nf > FLAG_CAP) nf = FLAG_CAP;
    const int tid = threadIdx.x;

    for (int chunk = blockIdx.x; chunk * 64 < nf; chunk += gridDim.x) {
        int cnt = nf - chunk * 64; if (cnt > 64) cnt = 64;
        if (tid < 64) {
            rowsS[tid] = flags[chunk * 64 + (tid < cnt ? tid : 0)];
            newS[tid] = -1;
        }
        __syncthreads();
#pragma unroll
        for (int i = 0; i < 16; ++i) {
            int f = tid + 256 * i;
            int r = f >> 6, c4 = f & 63;
            float4 v = *(const float4*)&inp[(size_t)rowsS[r] * DIM + c4 * 4];
            XsT[c4 * 4 + 0][r] = v.x; XsT[c4 * 4 + 1][r] = v.y;
            XsT[c4 * 4 + 2][r] = v.z; XsT[c4 * 4 + 3][r] = v.w;
        }
        __syncthreads();

        const int tx = tid & 15, ty = tid >> 4;
        float bv[4]; int bi[4];
#pragma unroll
        for (int mi = 0; mi < 4; ++mi) { bv[mi] = -1e30f; bi[mi] = 0x7fffffff; }
        for (int n0 = 0; n0 < NE; n0 += 64) {
            float acc[4][4] = {};
            const float* bp = embed + n0 + tx * 4;
            const float* ap = &XsT[0][ty * 4];
#pragma unroll 8
            for (int k = 0; k < DIM; ++k) {
                float4 b4 = *(const float4*)(bp + (size_t)k * NE);
                float4 a4 = *(const float4*)(ap + k * 64);
                acc[0][0] = fmaf(a4.x, b4.x, acc[0][0]); acc[0][1] = fmaf(a4.x, b4.y, acc[0][1]);
                acc[0][2] = fmaf(a4.x, b4.z, acc[0][2]); acc[0][3] = fmaf(a4.x, b4.w, acc[0][3]);
                acc[1][0] = fmaf(a4.y, b4.x, acc[1][0]); acc[1][1] = fmaf(a4.y, b4.y, acc[1][1]);
                acc[1][2] = fmaf(a4.y, b4.z, acc[1][2]); acc[1][3] = fmaf(a4.y, b4.w, acc[1][3]);
                acc[2][0] = fmaf(a4.z, b4.x, acc[2][0]); acc[2][1] = fmaf(a4.z, b4.y, acc[2][1]);
                acc[2][2] = fmaf(a4.z, b4.z, acc[2][2]); acc[2][3] = fmaf(a4.z, b4.w, acc[2][3]);
                acc[3][0] = fmaf(a4.w, b4.x, acc[3][0]); acc[3][1] = fmaf(a4.w, b4.y, acc[3][1]);
                acc[3][2] = fmaf(a4.w, b4.z, acc[3][2]); acc[3][3] = fmaf(a4.w, b4.w, acc[3][3]);
            }
            float4 en4 = *(const float4*)&enorm[n0 + tx * 4];
            int c0 = n0 + tx * 4;
#pragma unroll
            for (int mi = 0; mi < 4; ++mi) {
                float s0 = 2.f * acc[mi][0] - en4.x, s1 = 2.f * acc[mi][1] - en4.y;
                float s2 = 2.f * acc[mi][2] - en4.z, s3 = 2.f * acc[mi][3] - en4.w;
                float v = s0; int idx = c0;
                if (s1 > v) { v = s1; idx = c0 + 1; }
                if (s2 > v) { v = s2; idx = c0 + 2; }
                if (s3 > v) { v = s3; idx = c0 + 3; }
#pragma unroll
                for (int o = 1; o < 16; o <<= 1) {
                    float ov = __shfl_xor(v, o, 64); int oi = __shfl_xor(idx, o, 64);
                    if (ov > v || (ov == v && oi < idx)) { v = ov; idx = oi; }
                }
                if (v > bv[mi] || (v == bv[mi] && idx < bi[mi])) { bv[mi] = v; bi[mi] = idx; }
            }
        }
        if (tx == 0) {
#pragma unroll
            for (int mi = 0; mi < 4; ++mi) {
                int rl = ty * 4 + mi;
                if (rl < cnt) {
                    int row  = rowsS[rl];
                    int oldw = (int)out[OFF_IND + row];
                    if (bi[mi] != oldw) newS[rl] = bi[mi];
                }
            }
        }
        __syncthreads();

        // fixups (rare; newS is block-uniform so barriers are safe)
        for (int r = 0; r < 64; ++r) {
            int nw = newS[r];
            if (nw < 0) continue;
            int row  = rowsS[r];
            int oldw = (int)out[OFF_IND + row];
            float x   = XsT[tid][r];
            float env = embedT[(size_t)nw   * DIM + tid];
            float eov = embedT[(size_t)oldw * DIM + tid];
            out[(size_t)row * DIM + tid] = env;
            float dn = env - x;
            float dov = eov - x;
            double d = (double)(dn * dn) - (double)(dov * dov);
#pragma unroll
            for (int msk = 1; msk < 64; msk <<= 1) d += __shfl_xor(d, msk);
            if ((tid & 63) == 0) redS[tid >> 6] = d;
            __syncthreads();
            if (tid == 0) {
                atomicAdd(diffacc, redS[0] + redS[1] + redS[2] + redS[3]);
                atomicAdd(&counts[oldw], -1);
                atomicAdd(&counts[nw], 1);
                out[OFF_IND + row] = (float)nw;
            }
            __syncthreads();
        }
        __syncthreads();
    }
}

// ---------------- finalize ----------------
__global__ __launch_bounds__(256) void k_fin(const int* __restrict__ counts,
                                             const double* __restrict__ diffacc,
                                             float* __restrict__ out) {
    __shared__ double red[4];
    int tid = threadIdx.x;
    double s = 0.0;
    for (int i = tid; i < NE; i += 256) {
        int c = counts[i];
        if (c > 0) {
            float p = (float)c * (1.0f / 65536.0f);
            s += (double)(p * logf(p));
        }
    }
#pragma unroll
    for (int o = 32; o > 0; o >>= 1) s += __shfl_down(s, o, 64);
    if ((tid & 63) == 0) red[tid >> 6] = s;
    __syncthreads();
    if (tid == 0) {
        double t = red[0] + red[1] + red[2] + red[3];
        out[OFF_PERP] = expf((float)(-t));
        out[OFF_DIFF] = (float)(diffacc[0] * (1.0 / 16777216.0));
    }
}

extern "C" void kernel_launch(void* const* d_in, const int* in_sizes, int n_in,
                              void* d_out, int out_size, void* d_ws, size_t ws_size,
                              hipStream_t stream) {
    (void)in_sizes; (void)n_in; (void)out_size; (void)ws_size;
    const float* inp   = (const float*)d_in[0];
    const float* embed = (const float*)d_in[1];
    float* out = (float*)d_out;
    char*  ws  = (char*)d_ws;

    double*   diffacc = (double*)(ws + WS_DIFF);
    int*      nflag   = (int*)(ws + WS_NFLAG);
    int*      counts  = (int*)(ws + WS_CNT);
    float*    enorm   = (float*)(ws + WS_EN);
    int*      flags   = (int*)(ws + WS_FLAG);
    float*    embedT  = (float*)(ws + WS_ET);
    _Float16* bph     = (_Float16*)(ws + WS_BPH);

    (void)hipMemsetAsync(d_ws, 0, 8256, stream);   // diffacc + nflag + counts
    k_prep<<<NE / 32, 256, 0, stream>>>(embed, enorm);
    k_pack<<<256, 256, 0, stream>>>(embed, bph, embedT);
    k_gemm<<<NROWS / 128, 256, 0, stream>>>(inp, bph, enorm, embedT,
                                            out, counts, diffacc, nflag, flags);
    k_clean<<<64, 256, 0, stream>>>(inp, embed, embedT, enorm,
                                    out, counts, diffacc, nflag, flags);
    k_fin<<<1, 256, 0, stream>>>(counts, diffacc, out);
}

// Round 6
// 488.934 us; speedup vs baseline: 1.6955x; 1.6955x over previous
//
#include <hip/hip_runtime.h>
#include <cstdint>
#include <cstddef>

#define DIM    256
#define NE     2048
#define NROWS  65536

// d_out flat fp32 layout: quantize_st | diff | embed_ind | perplexity
#define OFF_DIFF ((size_t)16777216)
#define OFF_IND  ((size_t)16777217)
#define OFF_PERP ((size_t)16842753)

// d_ws byte layout
#define WS_DIFF   0                       // double
#define WS_NFLAG  8                       // int
#define WS_CNT    64                      // int[2048]
#define WS_EN     8256                    // float[2048]  ||e||^2
#define WS_FLAG   16448                   // int[4096] flagged rows
#define WS_ET     32832                   // float[2048*256] embedT
#define WS_BPH    2129984                 // _Float16[2048*256] packed B hi
#define FLAG_CAP  4096

typedef __attribute__((ext_vector_type(8)))  _Float16 half8;
typedef __attribute__((ext_vector_type(16))) float    float16v;

__device__ __forceinline__ float16v mfma32(half8 a, half8 b, float16v c) {
    return __builtin_amdgcn_mfma_f32_32x32x16_f16(a, b, c, 0, 0, 0);
}

// ---------------- prep: ||e_j||^2, double-accurate, 8 threads/col ----------------
__global__ __launch_bounds__(256) void k_prep(const float* __restrict__ embed,
                                              float* __restrict__ enorm) {
    __shared__ double red[256];
    const int tid = threadIdx.x;
    const int cl  = tid & 31, seg = tid >> 5;
    const int col = blockIdx.x * 32 + cl;
    double s = 0.0;
#pragma unroll 8
    for (int k = seg * 32; k < seg * 32 + 32; ++k) {
        float e = embed[(size_t)k * NE + col];
        s += (double)e * (double)e;
    }
    red[tid] = s;
    __syncthreads();
    if (seg == 0) {
        double t = 0.0;
#pragma unroll
        for (int h = 0; h < 8; ++h) t += red[cl + 32 * h];
        enorm[col] = (float)t;
    }
}

// ---------------- pack B-hi into 32x32x16 fragment order + embedT ----------------
// lane holds B[k = tfrag*16 + (lane>>5)*8 + j][col = nc*32 + (lane&31)], j=0..7
__global__ __launch_bounds__(256) void k_pack(const float* __restrict__ embed,
                                              _Float16* __restrict__ bph,
                                              float* __restrict__ embedT) {
    int tt    = blockIdx.x * 256 + threadIdx.x;   // 0..65535
    int nc    = tt >> 10;
    int tfrag = (tt >> 6) & 15;
    int lane  = tt & 63;
    int col   = nc * 32 + (lane & 31);
    int k0    = tfrag * 16 + (lane >> 5) * 8;
    half8 h;
#pragma unroll
    for (int j = 0; j < 8; ++j) {
        float e = embed[(size_t)(k0 + j) * NE + col];
        h[j] = (_Float16)e;
        embedT[(size_t)col * DIM + k0 + j] = e;
    }
    *(half8*)((char*)bph + (size_t)nc * 16384 + (size_t)tfrag * 1024 + (size_t)lane * 16) = h;
}

// ---------------- main fused MFMA kernel: 1-term, barrier-free, LDS-free ----------------
__global__ __launch_bounds__(256, 2) void k_gemm(
    const float* __restrict__ inp,
    const _Float16* __restrict__ bph,
    const float* __restrict__ enorm,
    const float* __restrict__ embedT,
    float* __restrict__ out,
    int* __restrict__ counts,
    double* __restrict__ diffacc,
    int* __restrict__ nflag,
    int* __restrict__ flags)
{
    const int tid  = threadIdx.x;
    const int w    = tid >> 6;
    const int lane = tid & 63;
    const int m    = lane & 31;       // col (B/C) or row (A) within tile
    const int mw   = blockIdx.x * 128 + w * 32;

    // ---- A: 32 rows/wave stationary, f16 (1-term; error covered by margin+cleanup) ----
    half8 ah[16];
    {
        const float* xr = inp + (size_t)(mw + m) * DIM + (lane >> 5) * 8;
#pragma unroll
        for (int t = 0; t < 16; ++t) {
            float4 f0 = *(const float4*)(xr + t * 16);
            float4 f1 = *(const float4*)(xr + t * 16 + 4);
            half8 hh;
            hh[0] = (_Float16)f0.x; hh[1] = (_Float16)f0.y;
            hh[2] = (_Float16)f0.z; hh[3] = (_Float16)f0.w;
            hh[4] = (_Float16)f1.x; hh[5] = (_Float16)f1.y;
            hh[6] = (_Float16)f1.z; hh[7] = (_Float16)f1.w;
            ah[t] = hh;
        }
    }

    // packed top-2 per C-reg slot
    int P1[16], P2[16];
#pragma unroll
    for (int r = 0; r < 16; ++r) { P1[r] = (int)0x80000000; P2[r] = (int)0x80000000; }

    for (int nc = 0; nc < 64; ++nc) {
        // B-fragments straight from L2-resident packed buffer (coalesced 1KB/load)
        const char* bp = (const char*)bph + (size_t)nc * 16384 + (size_t)lane * 16;
        half8 bf[16];
#pragma unroll
        for (int t = 0; t < 16; ++t) bf[t] = *(const half8*)(bp + t * 1024);

        float16v acc = {};
#pragma unroll
        for (int t = 0; t < 16; ++t) acc = mfma32(ah[t], bf[t], acc);

        float en  = enorm[nc * 32 + m];
        float enc = fmaf(en, -1024.0f, 262144.0f);   // (128 - en/2)*2048
        int colp  = nc * 32 + m;
#pragma unroll
        for (int r = 0; r < 16; ++r) {
            float sf = fmaf(acc[r], 2048.0f, enc);
            sf = __builtin_amdgcn_fmed3f(sf, -1048064.0f, 1048064.0f);
            int si = (int)sf;
            int p  = (int)(((unsigned)si << 11) | (unsigned)colp);
            int mn = (P1[r] < p) ? P1[r] : p;
            P2[r]  = (P2[r] > mn) ? P2[r] : mn;
            P1[r]  = (P1[r] > p) ? P1[r] : p;
        }
    }

    // ---- cross-lane top-2 merge over the 32 col-lanes (per half) ----
#pragma unroll
    for (int r = 0; r < 16; ++r) {
        int p1 = P1[r], p2 = P2[r];
#pragma unroll
        for (int msk = 1; msk < 32; msk <<= 1) {
            int o1 = __shfl_xor(p1, msk);
            int o2 = __shfl_xor(p2, msk);
            int mx2 = (p2 > o2) ? p2 : o2;
            int mn1 = (p1 < o1) ? p1 : o1;
            p2 = (mx2 > mn1) ? mx2 : mn1;
            p1 = (p1 > o1) ? p1 : o1;
        }
        P1[r] = p1; P2[r] = p2;
    }

    // ---- epilogue: exact fp32 rescore of top-2, margin flag, gather, write ----
    double dsum = 0.0;
#pragma unroll
    for (int rr = 0; rr < 32; ++rr) {
        const int reg = (rr & 3) | (((rr >> 3) & 3) << 2);
        const int src = ((rr >> 2) & 1) << 5;
        int p1row = __shfl(P1[reg], src);
        int p2row = __shfl(P2[reg], src);
        int i1 = p1row & 2047;
        int i2 = p2row & 2047;
        float v2a = (float)(p2row >> 11) * (1.0f / 1024.0f) - 256.0f;  // approx 2nd
        int row = mw + rr;
        float4 xv = *(const float4*)(inp    + (size_t)row * DIM + lane * 4);
        float4 e1 = *(const float4*)(embedT + (size_t)i1  * DIM + lane * 4);
        float4 e2 = *(const float4*)(embedT + (size_t)i2  * DIM + lane * 4);
        float d1 = xv.x * e1.x + xv.y * e1.y + xv.z * e1.z + xv.w * e1.w;
        float d2 = xv.x * e2.x + xv.y * e2.y + xv.z * e2.z + xv.w * e2.w;
#pragma unroll
        for (int msk = 1; msk < 64; msk <<= 1) {
            d1 += __shfl_xor(d1, msk);
            d2 += __shfl_xor(d2, msk);
        }
        float s1 = 2.f * d1 - enorm[i1];
        float s2 = 2.f * d2 - enorm[i2];
        bool take2 = (s2 > s1) || (s2 == s1 && i2 < i1);
        int win = take2 ? i2 : i1;
        float sW = take2 ? s2 : s1;
        float4 qv = take2 ? e2 : e1;
        *(float4*)(out + (size_t)row * DIM + lane * 4) = qv;
        float dx = qv.x - xv.x, dy = qv.y - xv.y;
        float dz = qv.z - xv.z, dw = qv.w - xv.w;
        dsum += (double)(dx * dx + dy * dy + dz * dz + dw * dw);
        if (lane == 0) {
            out[OFF_IND + row] = (float)win;
            atomicAdd(&counts[win], 1);
            if (sW - v2a < 0.15f) {          // untracked-column safety margin (~22 sigma)
                int fi = atomicAdd(nflag, 1);
                if (fi < FLAG_CAP) flags[fi] = row;
            }
        }
    }
#pragma unroll
    for (int msk = 1; msk < 64; msk <<= 1) dsum += __shfl_xor(dsum, msk);
    if (lane == 0) atomicAdd(diffacc, dsum);
}

// ---------------- cleanup v2: one wave per flagged row, exact fp32 rescan ----------------
__global__ __launch_bounds__(256) void k_clean(
    const float* __restrict__ inp,
    const float* __restrict__ embed,
    const float* __restrict__ embedT,
    const float* __restrict__ enorm,
    float* __restrict__ out,
    int* __restrict__ counts,
    double* __restrict__ diffacc,
    const int* __restrict__ nflagp,
    const int* __restrict__ flags)
{
    int nf = *nflagp; if (nf > FLAG_CAP) nf = FLAG_CAP;
    const int tid  = threadIdx.x;
    const int w    = tid >> 6;
    const int lane = tid & 63;

    for (int i = blockIdx.x * 4 + w; i < nf; i += gridDim.x * 4) {
        int row = flags[i];
        float4 x4 = *(const float4*)(inp + (size_t)row * DIM + lane * 4);

        float acc[32];
#pragma unroll
        for (int j = 0; j < 32; ++j) acc[j] = 0.f;

        // k-outer: broadcast x[k] from owning lane; coalesced row-major embed reads.
        for (int kb = 0; kb < 64; ++kb) {
            float xk0 = __shfl(x4.x, kb);
            float xk1 = __shfl(x4.y, kb);
            float xk2 = __shfl(x4.z, kb);
            float xk3 = __shfl(x4.w, kb);
            const float* eb = embed + (size_t)kb * 4 * NE + lane * 4;
#pragma unroll
            for (int j = 0; j < 8; ++j) {
                float4 b0 = *(const float4*)(eb + j * 256);
                float4 b1 = *(const float4*)(eb + NE + j * 256);
                float4 b2 = *(const float4*)(eb + 2 * NE + j * 256);
                float4 b3 = *(const float4*)(eb + 3 * NE + j * 256);
                acc[j * 4 + 0] = fmaf(xk0, b0.x, acc[j * 4 + 0]);
                acc[j * 4 + 1] = fmaf(xk0, b0.y, acc[j * 4 + 1]);
                acc[j * 4 + 2] = fmaf(xk0, b0.z, acc[j * 4 + 2]);
                acc[j * 4 + 3] = fmaf(xk0, b0.w, acc[j * 4 + 3]);
                acc[j * 4 + 0] = fmaf(xk1, b1.x, acc[j * 4 + 0]);
                acc[j * 4 + 1] = fmaf(xk1, b1.y, acc[j * 4 + 1]);
                acc[j * 4 + 2] = fmaf(xk1, b1.z, acc[j * 4 + 2]);
                acc[j * 4 + 3] = fmaf(xk1, b1.w, acc[j * 4 + 3]);
                acc[j * 4 + 0] = fmaf(xk2, b2.x, acc[j * 4 + 0]);
                acc[j * 4 + 1] = fmaf(xk2, b2.y, acc[j * 4 + 1]);
                acc[j * 4 + 2] = fmaf(xk2, b2.z, acc[j * 4 + 2]);
                acc[j * 4 + 3] = fmaf(xk2, b2.w, acc[j * 4 + 3]);
                acc[j * 4 + 0] = fmaf(xk3, b3.x, acc[j * 4 + 0]);
                acc[j * 4 + 1] = fmaf(xk3, b3.y, acc[j * 4 + 1]);
                acc[j * 4 + 2] = fmaf(xk3, b3.z, acc[j * 4 + 2]);
                acc[j * 4 + 3] = fmaf(xk3, b3.w, acc[j * 4 + 3]);
            }
        }

        // exact argmax (first-index tie-break): per-lane cols ascend with (j,c)
        float bv = -3.4e38f; int bi = 0x7fffffff;
#pragma unroll
        for (int j = 0; j < 8; ++j)
#pragma unroll
            for (int c = 0; c < 4; ++c) {
                int col = lane * 4 + c + 256 * j;
                float s = 2.f * acc[j * 4 + c] - enorm[col];
                if (s > bv) { bv = s; bi = col; }
            }
#pragma unroll
        for (int msk = 1; msk < 64; msk <<= 1) {
            float ov = __shfl_xor(bv, msk);
            int   oi = __shfl_xor(bi, msk);
            if (ov > bv || (ov == bv && oi < bi)) { bv = ov; bi = oi; }
        }

        int oldw = (int)out[OFF_IND + row];
        if (bi != oldw) {          // wave-uniform branch; fixup everything
            float4 env = *(const float4*)(embedT + (size_t)bi   * DIM + lane * 4);
            float4 eov = *(const float4*)(embedT + (size_t)oldw * DIM + lane * 4);
            *(float4*)(out + (size_t)row * DIM + lane * 4) = env;
            float nx = env.x - x4.x, ny = env.y - x4.y, nz = env.z - x4.z, nw2 = env.w - x4.w;
            float ox = eov.x - x4.x, oy = eov.y - x4.y, oz = eov.z - x4.z, ow = eov.w - x4.w;
            double d = (double)(nx * nx + ny * ny + nz * nz + nw2 * nw2)
                     - (double)(ox * ox + oy * oy + oz * oz + ow * ow);
#pragma unroll
            for (int msk = 1; msk < 64; msk <<= 1) d += __shfl_xor(d, msk);
            if (lane == 0) {
                atomicAdd(diffacc, d);
                atomicAdd(&counts[oldw], -1);
                atomicAdd(&counts[bi], 1);
                out[OFF_IND + row] = (float)bi;
            }
        }
    }
}

// ---------------- finalize ----------------
__global__ __launch_bounds__(256) void k_fin(const int* __restrict__ counts,
                                             const double* __restrict__ diffacc,
                                             float* __restrict__ out) {
    __shared__ double red[4];
    int tid = threadIdx.x;
    double s = 0.0;
    for (int i = tid; i < NE; i += 256) {
        int c = counts[i];
        if (c > 0) {
            float p = (float)c * (1.0f / 65536.0f);
            s += (double)(p * logf(p));
        }
    }
#pragma unroll
    for (int o = 32; o > 0; o >>= 1) s += __shfl_down(s, o, 64);
    if ((tid & 63) == 0) red[tid >> 6] = s;
    __syncthreads();
    if (tid == 0) {
        double t = red[0] + red[1] + red[2] + red[3];
        out[OFF_PERP] = expf((float)(-t));
        out[OFF_DIFF] = (float)(diffacc[0] * (1.0 / 16777216.0));
    }
}

extern "C" void kernel_launch(void* const* d_in, const int* in_sizes, int n_in,
                              void* d_out, int out_size, void* d_ws, size_t ws_size,
                              hipStream_t stream) {
    (void)in_sizes; (void)n_in; (void)out_size; (void)ws_size;
    const float* inp   = (const float*)d_in[0];
    const float* embed = (const float*)d_in[1];
    float* out = (float*)d_out;
    char*  ws  = (char*)d_ws;

    double*   diffacc = (double*)(ws + WS_DIFF);
    int*      nflag   = (int*)(ws + WS_NFLAG);
    int*      counts  = (int*)(ws + WS_CNT);
    float*    enorm   = (float*)(ws + WS_EN);
    int*      flags   = (int*)(ws + WS_FLAG);
    float*    embedT  = (float*)(ws + WS_ET);
    _Float16* bph     = (_Float16*)(ws + WS_BPH);

    (void)hipMemsetAsync(d_ws, 0, 8256, stream);   // diffacc + nflag + counts
    k_prep<<<NE / 32, 256, 0, stream>>>(embed, enorm);
    k_pack<<<256, 256, 0, stream>>>(embed, bph, embedT);
    k_gemm<<<NROWS / 128, 256, 0, stream>>>(inp, bph, enorm, embedT,
                                            out, counts, diffacc, nflag, flags);
    k_clean<<<256, 256, 0, stream>>>(inp, embed, embedT, enorm,
                                     out, counts, diffacc, nflag, flags);
    k_fin<<<1, 256, 0, stream>>>(counts, diffacc, out);
}